// Round 8
// baseline (381.589 us; speedup 1.0000x reference)
//
#include <hip/hip_runtime.h>

// GCN: 3 x (GCNConv -> BN(train) -> PReLU), N=100000, E=1600000, 128->64->64->64
// R17: partition_edges occupancy fix.
//   R16 post-mortem: reduce_bn fixed (out of top-5); new top kernel is
//   partition_edges 44us at Occ 6.8% (grid = E/8192 = 196 blocks < 1/CU).
//   Fix: PART_CHUNK 8192->2048 (782 blocks, ~3/CU) + register-cache the 8
//   dst values across the histogram/scatter passes. Global reserve atomics
//   rise to ~560K over 782 distinct addresses — pipelined, ~1-2us.
//   (262MB fillBufferAligned dispatches = harness workspace re-poison, not
//   in kernel_launch; ignored.)
// R16: single-shot reduce (grid 3125, one uint4/thread) + 16-slot striped
//   stats; consumers sum slots. reduce 46->~15us.
// R15/R13: windowed latency-flat gather (one col-latency + one row-latency per
//   (node,slice) unit, clamp-indexed windows of 4) + fp16 hs/y planes.
// R12: shuffle-free gather geometry (8-lane groups, full-lane epilogue).
// R11: FETCH=35MB == compulsory floor (8 XCD x 3.2MB slice + col).
// R10: src-sliced XCD-pinned gather; bid%8->XCD round-robin; CSR ordered
//   (bucket, local, slice): rowstart4[n*4+s].
// R9: bf16 MFMA GEMMs. R3: LDS-atomic aggregation = latency disaster.

constexpr float BN_EPS = 1e-5f;
constexpr int NB_SHIFT = 7;          // 128 nodes per bucket
constexpr int BCAP = 2560;           // pairs per bucket (avg 2048, ~11 sigma)
constexpr int PART_CHUNK = 2048;     // edges per partition block (R17: was 8192)
constexpr int NSLOT = 16;            // striped stats slots

typedef __bf16 bf16x8 __attribute__((ext_vector_type(8)));
typedef float floatx4 __attribute__((ext_vector_type(4)));
typedef _Float16 half4 __attribute__((ext_vector_type(4)));
typedef _Float16 h2v __attribute__((ext_vector_type(2)));
typedef unsigned uintx4 __attribute__((ext_vector_type(4)));

__device__ inline unsigned short f2bf(float f) {
    unsigned u = __float_as_uint(f);
    unsigned r = (u + 0x7FFFu + ((u >> 16) & 1u)) >> 16;
    return (unsigned short)r;
}
__device__ inline unsigned short f2h(float f) {
    _Float16 h = (_Float16)f;
    return __builtin_bit_cast(unsigned short, h);
}
__device__ inline float h2f(unsigned short u) {
    return (float)__builtin_bit_cast(_Float16, u);
}
__device__ inline unsigned pack_h2(float a, float b) {
    h2v h = {(_Float16)a, (_Float16)b};
    return __builtin_bit_cast(unsigned, h);
}
__device__ inline int slice_of(int idx, float s4f) {
    int s = (int)((float)idx * s4f);
    return s > 3 ? 3 : s;
}
// accumulate 8 fp16 (one uint4) into 8 fp32
__device__ inline void addu4(uint4 r, float* A) {
    h2v h0 = __builtin_bit_cast(h2v, r.x);
    h2v h1 = __builtin_bit_cast(h2v, r.y);
    h2v h2 = __builtin_bit_cast(h2v, r.z);
    h2v h3 = __builtin_bit_cast(h2v, r.w);
    A[0] += (float)h0[0]; A[1] += (float)h0[1];
    A[2] += (float)h1[0]; A[3] += (float)h1[1];
    A[4] += (float)h2[0]; A[5] += (float)h2[1];
    A[6] += (float)h3[0]; A[7] += (float)h3[1];
}

// Partition edges into 128-node dst-buckets; packed entry = src | (local<<20).
// R17: 2048-edge chunks (782 blocks), dst register-cached across passes.
__global__ __launch_bounds__(256) void partition_edges(
    const int* __restrict__ src, const int* __restrict__ dst,
    int* __restrict__ bcount, unsigned* __restrict__ pairs, int E, int nbuck) {
    __shared__ int hist[1024];
    const int t = threadIdx.x;
    for (int i = t; i < nbuck; i += 256) hist[i] = 0;
    __syncthreads();
    const int e0 = blockIdx.x * PART_CHUNK;
    const int e1 = min(e0 + PART_CHUNK, E);
    int dloc[PART_CHUNK / 256];
    int cnt = 0;
    for (int e = e0 + t; e < e1; e += 256) {
        int d = dst[e];
        dloc[cnt++] = d;
        atomicAdd(&hist[d >> NB_SHIFT], 1);
    }
    __syncthreads();
    for (int i = t; i < nbuck; i += 256) {
        int c = hist[i];
        hist[i] = (c > 0) ? atomicAdd(&bcount[i], c) : 0;  // run base within bucket
    }
    __syncthreads();
    cnt = 0;
    for (int e = e0 + t; e < e1; e += 256) {
        int s = src[e], d = dloc[cnt++];
        int b = d >> NB_SHIFT;
        int pos = atomicAdd(&hist[b], 1);
        pairs[(size_t)b * BCAP + pos] = (unsigned)s | ((unsigned)(d & 127) << 20);
    }
}

// Exclusive scan of bcount[nbuck] -> bbase; also rowstart4[4N] = E sentinel.
__global__ __launch_bounds__(1024) void scan_bcount(
    const int* __restrict__ bcount, int* __restrict__ bbase,
    int* __restrict__ rowstart4, int N, int E, int nbuck) {
    __shared__ int tmp[1024];
    const int t = threadIdx.x;
    int v = (t < nbuck) ? bcount[t] : 0;
    tmp[t] = v;
    __syncthreads();
    for (int off = 1; off < 1024; off <<= 1) {
        int u = (t >= off) ? tmp[t - off] : 0;
        __syncthreads();
        tmp[t] += u;
        __syncthreads();
    }
    if (t < nbuck) bbase[t] = tmp[t] - v;  // exclusive
    if (t == 0) rowstart4[4 * N] = E;
}

// One block per bucket: LDS (local,slice) histogram -> scan -> rowstart4/dinv,
// then cursor fill of col ordered by (local, slice) within the bucket window.
__global__ __launch_bounds__(256) void fill_csr_bucket(
    const unsigned* __restrict__ pairs, const int* __restrict__ bcount,
    const int* __restrict__ bbase, int* __restrict__ rowstart4,
    float* __restrict__ dinv, int* __restrict__ col, int N, float s4f) {
    __shared__ int hist[512], pfx[512];
    const int b = blockIdx.x, t = threadIdx.x;
    hist[t] = 0; hist[t + 256] = 0;
    __syncthreads();
    const int cnt = bcount[b];
    const unsigned* pp = pairs + (size_t)b * BCAP;
    for (int e = t; e < cnt; e += 256) {
        unsigned pr = pp[e];
        int srcv = (int)(pr & 0xFFFFFu);
        atomicAdd(&hist[((pr >> 20) << 2) + slice_of(srcv, s4f)], 1);
    }
    __syncthreads();
    pfx[t] = hist[t]; pfx[t + 256] = hist[t + 256];
    __syncthreads();
    for (int off = 1; off < 512; off <<= 1) {
        int v0 = (t >= off) ? pfx[t - off] : 0;
        int v1 = pfx[t + 256 - off];  // t+256 >= 256 >= off always
        __syncthreads();
        if (t >= off) pfx[t] += v0;
        pfx[t + 256] += v1;
        __syncthreads();
    }
    const int base = bbase[b];
    if (t < 128) {
        int excl0 = pfx[t * 4] - hist[t * 4];
        int degTot = pfx[t * 4 + 3] - excl0;
        int n = (b << NB_SHIFT) + t;
        if (n < N) dinv[n] = rsqrtf((float)degTot + 1.0f);  // +1 self-loop
    }
    __syncthreads();
    // per-(local,slice) start -> rowstart4 and cursor
    {
        int i0 = t, i1 = t + 256;
        int st0 = base + pfx[i0] - hist[i0];
        int st1 = base + pfx[i1] - hist[i1];
        int n0 = (b << NB_SHIFT) + (i0 >> 2);
        int n1 = (b << NB_SHIFT) + (i1 >> 2);
        if (n0 < N) rowstart4[(n0 << 2) + (i0 & 3)] = st0;
        if (n1 < N) rowstart4[(n1 << 2) + (i1 & 3)] = st1;
        hist[i0] = st0; hist[i1] = st1;
    }
    __syncthreads();
    for (int e = t; e < cnt; e += 256) {
        unsigned pr = pp[e];
        int srcv = (int)(pr & 0xFFFFFu);
        int pos = atomicAdd(&hist[((pr >> 20) << 2) + slice_of(srcv, s4f)], 1);
        col[pos] = srcv;
    }
}

// Transpose + bf16-convert all three W matrices: wt[n*K + k] = bf16(W[k][n]).
__global__ __launch_bounds__(256) void prep_wt_all(
    const float* __restrict__ W1, const float* __restrict__ W2,
    const float* __restrict__ W3, unsigned short* __restrict__ wt1,
    unsigned short* __restrict__ wt2, unsigned short* __restrict__ wt3) {
    const int b = blockIdx.x, t = threadIdx.x;
    const float* W;
    unsigned short* wt;
    int K, base;
    if (b < 32)      { W = W1; wt = wt1; K = 128; base = b * 256; }
    else if (b < 48) { W = W2; wt = wt2; K = 64;  base = (b - 32) * 256; }
    else             { W = W3; wt = wt3; K = 64;  base = (b - 48) * 256; }
    int i = base + t;
    if (i < K * 64) {
        int k = i >> 6, n = i & 63;
        wt[n * K + k] = f2bf(W[i]);
    }
}

// MFMA bf16 GEMM: hs[row][c] = fp16( (X'[row][:] @ W[:][c]) * dinv[row] ).
// FUSE: X' = prelu(bn(X), a), X stored fp16; scale/shift from 16-slot stats.
// Block: 256 thr = 4 waves; 64 rows x 64 cols; wave w owns rows 16w..16w+15.
template <int K, bool FUSE>
__global__ __launch_bounds__(256) void gemm_mfma(
    const float* __restrict__ X, const unsigned short* __restrict__ wt,
    const float* __restrict__ dinv, const float* __restrict__ stats_prev,
    const float* __restrict__ g_prev, const float* __restrict__ be_prev,
    const float* __restrict__ a_prev, float invN,
    ushort4* __restrict__ hsb4, int N) {
    constexpr int XS = K + 8;  // LDS row stride in bf16 units (pad 16B)
    __shared__ unsigned short Xs[64 * XS];
    __shared__ unsigned short Wts[64 * XS];
    __shared__ float scs[64], shs[64];

    const int t = threadIdx.x;
    const int rowBase = blockIdx.x * 64;

    if (FUSE && t < 64) {
        float ms = 0.f, qs = 0.f;
#pragma unroll
        for (int k = 0; k < NSLOT; ++k) {
            ms += stats_prev[k * 128 + t];
            qs += stats_prev[k * 128 + 64 + t];
        }
        float mu = ms * invN;
        float var = qs * invN - mu * mu;
        float sc = g_prev[t] * rsqrtf(var + BN_EPS);
        scs[t] = sc;
        shs[t] = fmaf(-mu, sc, be_prev[t]);
    }

    // stage Wt (64 rows x K bf16) via uint4
    constexpr int U4R = K / 8;  // uint4 per wt row
#pragma unroll
    for (int j = 0; j < (64 * U4R) / 256; ++j) {
        int idx = t + j * 256;
        int n = idx / U4R, ch = idx % U4R;
        uint4 v = *(const uint4*)&wt[n * K + ch * 8];
        *(uint4*)&Wts[n * XS + ch * 8] = v;
    }
    __syncthreads();  // scs + Wts visible

    // stage Xs: 64 rows x K -> (FUSE: fp16 + BN/PReLU) -> bf16
    constexpr int F4R = K / 4;  // 4-feature chunks per X row
#pragma unroll
    for (int j = 0; j < (64 * F4R) / 256; ++j) {
        int idx = t + j * 256;
        int r = idx / F4R, c4 = idx % F4R;
        int row = rowBase + r;
        float4 v = make_float4(0.f, 0.f, 0.f, 0.f);
        if (row < N) {
            if (FUSE) {
                const unsigned short* Xh = (const unsigned short*)X;
                uint2 hv = *(const uint2*)(Xh + (size_t)row * 64 + c4 * 4);
                h2v p = __builtin_bit_cast(h2v, hv.x);
                h2v q = __builtin_bit_cast(h2v, hv.y);
                v = make_float4((float)p[0], (float)p[1], (float)q[0], (float)q[1]);
                int c = c4 * 4;
                float4 av = ((const float4*)a_prev)[c4];
                v.x = fmaf(v.x, scs[c + 0], shs[c + 0]); v.x = v.x >= 0.f ? v.x : av.x * v.x;
                v.y = fmaf(v.y, scs[c + 1], shs[c + 1]); v.y = v.y >= 0.f ? v.y : av.y * v.y;
                v.z = fmaf(v.z, scs[c + 2], shs[c + 2]); v.z = v.z >= 0.f ? v.z : av.z * v.z;
                v.w = fmaf(v.w, scs[c + 3], shs[c + 3]); v.w = v.w >= 0.f ? v.w : av.w * v.w;
            } else {
                v = *(const float4*)(X + (size_t)row * K + c4 * 4);
            }
        }
        ushort4 o;
        o.x = f2bf(v.x); o.y = f2bf(v.y); o.z = f2bf(v.z); o.w = f2bf(v.w);
        *(ushort4*)&Xs[r * XS + c4 * 4] = o;
    }
    __syncthreads();

    const int w = t >> 6;        // wave 0..3 -> rows 16w..16w+15
    const int l = t & 63;
    const int q = l >> 4;        // quad: k-offset q*8
    const int m = l & 15;        // A row / B col within tile

    floatx4 acc[4];
#pragma unroll
    for (int ct = 0; ct < 4; ++ct) acc[ct] = {0.f, 0.f, 0.f, 0.f};

#pragma unroll
    for (int ks = 0; ks < K / 32; ++ks) {
        bf16x8 a = *(const bf16x8*)&Xs[(16 * w + m) * XS + ks * 32 + q * 8];
#pragma unroll
        for (int ct = 0; ct < 4; ++ct) {
            bf16x8 b = *(const bf16x8*)&Wts[(ct * 16 + m) * XS + ks * 32 + q * 8];
            acc[ct] = __builtin_amdgcn_mfma_f32_16x16x32_bf16(a, b, acc[ct], 0, 0, 0);
        }
    }

    // dinv per owned row (C/D layout: row = q*4 + r, col = m)
    float dv[4];
#pragma unroll
    for (int r = 0; r < 4; ++r) {
        int row = rowBase + 16 * w + q * 4 + r;
        dv[r] = (row < N) ? dinv[row] : 0.f;
    }

    __syncthreads();  // done reading Xs; reuse as C staging (64 x 72 fp16)
    unsigned short* Cs = Xs;
#pragma unroll
    for (int ct = 0; ct < 4; ++ct)
#pragma unroll
        for (int r = 0; r < 4; ++r)
            Cs[(16 * w + q * 4 + r) * 72 + ct * 16 + m] = f2h(acc[ct][r] * dv[r]);
    __syncthreads();

    // coalesced write-out: 64 rows x 8 uint4 (row = 64 fp16)
#pragma unroll
    for (int j = 0; j < 2; ++j) {
        int idx = t + j * 256;
        int r = idx >> 3, ch = idx & 7;
        int row = rowBase + r;
        if (row < N) {
            uint4 v = *(const uint4*)&Cs[r * 72 + ch * 8];
            ((uint4*)hsb4)[(size_t)row * 8 + ch] = v;
        }
    }
}

// Gather: block group g = bid&7 -> slice s = g>>1, node-half h = g&1
// (bid%8 -> XCD round-robin keeps each XCD on one 3.2MB L2-resident slice).
// 8-lane group owns one (node,slice): lane = feature octet (16B), wave = 8
// consecutive nodes. Windowed: 4 clamp-indexed col loads together, then 4 row
// loads together (zero-masked past deg); windows at deg>4/>8, serial tail >12.
// Self term added by the slice containing n (L2-hit). 1KB contiguous NT stores.
__global__ __launch_bounds__(256) void aggregate_sliced(
    const uint4* __restrict__ hsp, const int* __restrict__ col,
    const int* __restrict__ rs4, uint4* __restrict__ parts, int N, float s4f) {
    const int t = threadIdx.x;
    const int lane = t & 63;
    const int wid = t >> 6;      // wave in block (0..3)
    const int fl = lane & 7;     // feature octet index (16B)
    const int grp = lane >> 3;   // node subgroup (0..7)
    const int g = blockIdx.x & 7;
    const int s = g >> 1;        // src slice 0..3
    const int h = g & 1;         // node half
    const int r = blockIdx.x >> 3;
    const int H = (N + 1) >> 1;
    const int n0 = h * H;
    const int n1 = min(N, n0 + H);
    const int stride = ((gridDim.x >> 3) << 2) << 3;  // waves/group * 8 nodes
    uint4* plane = parts + (size_t)s * ((size_t)N * 8);

    for (int nb = n0 + (((r << 2) + wid) << 3); nb < n1; nb += stride) {
        const int n = nb + grp;
        const bool valid = n < n1;
        int start = 0, deg = 0;
        if (valid) {
            start = rs4[(n << 2) + s];
            deg = rs4[(n << 2) + s + 1] - start;
        }
        float A[8] = {0.f, 0.f, 0.f, 0.f, 0.f, 0.f, 0.f, 0.f};
        float B[8] = {0.f, 0.f, 0.f, 0.f, 0.f, 0.f, 0.f, 0.f};
        const uint4 z = {0u, 0u, 0u, 0u};
#pragma unroll
        for (int wnd = 0; wnd < 3; ++wnd) {
            const int o = wnd * 4;
            if (deg > o) {
                int d1 = deg - 1;
                int j1 = min(o + 1, d1), j2 = min(o + 2, d1), j3 = min(o + 3, d1);
                int e0 = col[start + o];
                int e1 = col[start + j1];
                int e2 = col[start + j2];
                int e3 = col[start + j3];
                uint4 r0 = hsp[(size_t)e0 * 8 + fl];
                uint4 r1 = hsp[(size_t)e1 * 8 + fl];
                uint4 r2 = hsp[(size_t)e2 * 8 + fl];
                uint4 r3 = hsp[(size_t)e3 * 8 + fl];
                if (o + 1 >= deg) r1 = z;
                if (o + 2 >= deg) r2 = z;
                if (o + 3 >= deg) r3 = z;
                addu4(r0, A); addu4(r1, B); addu4(r2, A); addu4(r3, B);
            }
        }
        for (int it = 12; it < deg; ++it) {  // P(deg>12) ~ 0.06%
            int e0 = col[start + it];
            addu4(hsp[(size_t)e0 * 8 + fl], A);
        }
        if (valid && slice_of(n, s4f) == s) {  // self term, slice-local (L2-hit)
            addu4(hsp[(size_t)n * 8 + fl], B);
        }
        if (valid) {
            uintx4 ov;
            ov[0] = pack_h2(A[0] + B[0], A[1] + B[1]);
            ov[1] = pack_h2(A[2] + B[2], A[3] + B[3]);
            ov[2] = pack_h2(A[4] + B[4], A[5] + B[5]);
            ov[3] = pack_h2(A[6] + B[6], A[7] + B[7]);
            __builtin_nontemporal_store(ov, (uintx4*)&plane[(size_t)n * 8 + fl]);
        }
    }
}

// Single-shot reduce: grid = N*8/256 blocks, one uint4 position per thread
// (node = i>>3, feature octet = i&7). y = dinv*(sum_s parts[s]) + bias (self
// already in planes). Stats: shfl_xor(8/16/32) wave pre-reduce -> LDS ->
// 16-slot striped global atomics (consumers sum the slots).
__global__ __launch_bounds__(256) void reduce_bn(
    const uint4* __restrict__ parts, const float* __restrict__ dinv,
    const float* __restrict__ bias, float* __restrict__ stats,
    uint4* __restrict__ y4h, int N) {
    const int t = threadIdx.x;
    const size_t NP4 = (size_t)N * 8;
    const size_t i = (size_t)blockIdx.x * 256 + t;
    const int fo = (int)(i & 7);  // feature octet (features fo*8 .. fo*8+7)
    __shared__ float lsum[64], lsq[64];
    if (t < 64) { lsum[t] = 0.f; lsq[t] = 0.f; }
    __syncthreads();

    float S[8] = {0.f, 0.f, 0.f, 0.f, 0.f, 0.f, 0.f, 0.f};
    float Q[8] = {0.f, 0.f, 0.f, 0.f, 0.f, 0.f, 0.f, 0.f};
    if (i < NP4) {
        uint4 p0 = parts[i];
        uint4 p1 = parts[NP4 + i];
        uint4 p2 = parts[2 * NP4 + i];
        uint4 p3 = parts[3 * NP4 + i];
        float dv = dinv[i >> 3];
        float4 bA = ((const float4*)bias)[fo * 2];
        float4 bB = ((const float4*)bias)[fo * 2 + 1];
        float bb[8] = {bA.x, bA.y, bA.z, bA.w, bB.x, bB.y, bB.z, bB.w};
        unsigned u0[4] = {p0.x, p0.y, p0.z, p0.w};
        unsigned u1[4] = {p1.x, p1.y, p1.z, p1.w};
        unsigned u2[4] = {p2.x, p2.y, p2.z, p2.w};
        unsigned u3[4] = {p3.x, p3.y, p3.z, p3.w};
        uintx4 ov;
#pragma unroll
        for (int k = 0; k < 4; ++k) {
            h2v a = __builtin_bit_cast(h2v, u0[k]);
            h2v b = __builtin_bit_cast(h2v, u1[k]);
            h2v c = __builtin_bit_cast(h2v, u2[k]);
            h2v d = __builtin_bit_cast(h2v, u3[k]);
            float y0 = fmaf(dv, (float)a[0] + (float)b[0] + (float)c[0] + (float)d[0], bb[2 * k]);
            float y1 = fmaf(dv, (float)a[1] + (float)b[1] + (float)c[1] + (float)d[1], bb[2 * k + 1]);
            S[2 * k] = y0; Q[2 * k] = y0 * y0;
            S[2 * k + 1] = y1; Q[2 * k + 1] = y1 * y1;
            ov[k] = pack_h2(y0, y1);
        }
        *(uintx4*)&y4h[i] = ov;
    }
    // wave reduce across lanes with the same (lane&7) == feature octet
#pragma unroll
    for (int k = 0; k < 8; ++k) {
        S[k] += __shfl_xor(S[k], 8);  Q[k] += __shfl_xor(Q[k], 8);
        S[k] += __shfl_xor(S[k], 16); Q[k] += __shfl_xor(Q[k], 16);
        S[k] += __shfl_xor(S[k], 32); Q[k] += __shfl_xor(Q[k], 32);
    }
    if ((t & 63) < 8) {
        const int base = (t & 7) * 8;
#pragma unroll
        for (int k = 0; k < 8; ++k) {
            atomicAdd(&lsum[base + k], S[k]);
            atomicAdd(&lsq[base + k], Q[k]);
        }
    }
    __syncthreads();
    const int slot = blockIdx.x & (NSLOT - 1);
    if (t < 64) atomicAdd(&stats[slot * 128 + t], lsum[t]);
    else if (t < 128) atomicAdd(&stats[slot * 128 + 64 + (t - 64)], lsq[t - 64]);
}

// Fallback (ws too small for planes): single-pass aggregate, fp16 hs/y,
// 16-slot striped stats.
__global__ __launch_bounds__(256) void aggregate_bn(
    const ushort4* __restrict__ hsb4, const int* __restrict__ col,
    const int* __restrict__ rs4, const float* __restrict__ dinv,
    const float* __restrict__ bias, float* __restrict__ stats,
    uint2* __restrict__ y2, int N) {
    const int t = threadIdx.x;
    const int lane = t & 63;
    const int wid = t >> 6;
    const int fl = lane & 15;
    const int eg = lane >> 4;

    __shared__ float lsum[64], lsq[64];
    if (t < 64) { lsum[t] = 0.f; lsq[t] = 0.f; }
    __syncthreads();

    float4 ssum = make_float4(0.f, 0.f, 0.f, 0.f);
    float4 ssq  = make_float4(0.f, 0.f, 0.f, 0.f);
    const float4 b4 = ((const float4*)bias)[fl];
    const int waveStride = gridDim.x * 4;

    for (int n = blockIdx.x * 4 + wid; n < N; n += waveStride) {
        int start = rs4[n * 4];
        int deg = rs4[n * 4 + 4] - start;
        float4 acc = make_float4(0.f, 0.f, 0.f, 0.f);
        for (int i = eg; i < deg; i += 4) {
            int s = col[start + i];
            ushort4 rv = hsb4[(size_t)s * 16 + fl];
            acc.x += h2f(rv.x); acc.y += h2f(rv.y);
            acc.z += h2f(rv.z); acc.w += h2f(rv.w);
        }
        acc.x += __shfl_xor(acc.x, 16); acc.y += __shfl_xor(acc.y, 16);
        acc.z += __shfl_xor(acc.z, 16); acc.w += __shfl_xor(acc.w, 16);
        acc.x += __shfl_xor(acc.x, 32); acc.y += __shfl_xor(acc.y, 32);
        acc.z += __shfl_xor(acc.z, 32); acc.w += __shfl_xor(acc.w, 32);
        if (eg == 0) {
            ushort4 sv = hsb4[(size_t)n * 16 + fl];
            float dv = dinv[n];
            float yx = fmaf(dv, acc.x + h2f(sv.x), b4.x);
            float yy = fmaf(dv, acc.y + h2f(sv.y), b4.y);
            float yz = fmaf(dv, acc.z + h2f(sv.z), b4.z);
            float yw = fmaf(dv, acc.w + h2f(sv.w), b4.w);
            uint2 yv;
            yv.x = pack_h2(yx, yy);
            yv.y = pack_h2(yz, yw);
            y2[(size_t)n * 16 + fl] = yv;
            ssum.x += yx; ssum.y += yy; ssum.z += yz; ssum.w += yw;
            ssq.x = fmaf(yx, yx, ssq.x); ssq.y = fmaf(yy, yy, ssq.y);
            ssq.z = fmaf(yz, yz, ssq.z); ssq.w = fmaf(yw, yw, ssq.w);
        }
    }
    if (eg == 0) {
        atomicAdd(&lsum[fl * 4 + 0], ssum.x); atomicAdd(&lsum[fl * 4 + 1], ssum.y);
        atomicAdd(&lsum[fl * 4 + 2], ssum.z); atomicAdd(&lsum[fl * 4 + 3], ssum.w);
        atomicAdd(&lsq[fl * 4 + 0], ssq.x);  atomicAdd(&lsq[fl * 4 + 1], ssq.y);
        atomicAdd(&lsq[fl * 4 + 2], ssq.z);  atomicAdd(&lsq[fl * 4 + 3], ssq.w);
    }
    __syncthreads();
    const int slot = blockIdx.x & (NSLOT - 1);
    if (t < 64) atomicAdd(&stats[slot * 128 + t], lsum[t]);
    else if (t < 128) atomicAdd(&stats[slot * 128 + 64 + (t - 64)], lsq[t - 64]);
}

// final layer: out = prelu(bn(y), a), y fp16, scale/shift from 16-slot stats
// (precomputed once per block into LDS).
__global__ __launch_bounds__(256) void bn_apply(
    const uint2* __restrict__ y2, const float* __restrict__ stats,
    const float* __restrict__ g, const float* __restrict__ be,
    const float* __restrict__ a, float invN, float4* __restrict__ out4,
    int total4) {
    __shared__ float scs[64], shs[64], as[64];
    const int t = threadIdx.x;
    if (t < 64) {
        float ms = 0.f, qs = 0.f;
#pragma unroll
        for (int k = 0; k < NSLOT; ++k) {
            ms += stats[k * 128 + t];
            qs += stats[k * 128 + 64 + t];
        }
        float mu = ms * invN;
        float var = qs * invN - mu * mu;
        float sc = g[t] * rsqrtf(var + BN_EPS);
        scs[t] = sc;
        shs[t] = fmaf(-mu, sc, be[t]);
        as[t] = a[t];
    }
    __syncthreads();
    int i = blockIdx.x * blockDim.x + t;
    if (i >= total4) return;
    int cg = (i & 15) * 4;
    uint2 hv = y2[i];
    h2v p = __builtin_bit_cast(h2v, hv.x);
    h2v q = __builtin_bit_cast(h2v, hv.y);
    float vv[4] = {(float)p[0], (float)p[1], (float)q[0], (float)q[1]};
    float4 o;
#pragma unroll
    for (int j = 0; j < 4; ++j) {
        int c = cg + j;
        float z = fmaf(vv[j], scs[c], shs[c]);
        z = z >= 0.f ? z : as[c] * z;
        if (j == 0) o.x = z; else if (j == 1) o.y = z; else if (j == 2) o.z = z; else o.w = z;
    }
    out4[i] = o;
}

extern "C" void kernel_launch(void* const* d_in, const int* in_sizes, int n_in,
                              void* d_out, int out_size, void* d_ws, size_t ws_size,
                              hipStream_t stream) {
    const float* x  = (const float*)d_in[0];
    const int*   ei = (const int*)d_in[1];
    const int N = in_sizes[0] / 128;
    const int E = in_sizes[1] / 2;
    const int* srcp = ei;
    const int* dstp = ei + E;

    const float* W1 = (const float*)d_in[2];
    const float* b1 = (const float*)d_in[3];
    const float* g1 = (const float*)d_in[4];
    const float* be1 = (const float*)d_in[5];
    const float* a1 = (const float*)d_in[6];
    const float* W2 = (const float*)d_in[7];
    const float* b2 = (const float*)d_in[8];
    const float* g2 = (const float*)d_in[9];
    const float* be2 = (const float*)d_in[10];
    const float* a2 = (const float*)d_in[11];
    const float* W3 = (const float*)d_in[12];
    const float* b3 = (const float*)d_in[13];
    const float* g3 = (const float*)d_in[14];
    const float* be3 = (const float*)d_in[15];
    const float* a3 = (const float*)d_in[16];

    const int nbuck = (N + 127) >> NB_SHIFT;  // 782
    const float s4f = 4.0f / (float)N;

    // ws layout (4B units):
    // dinv[N] | rowstart4[4N+4] | bcount[1024] | bbase[1024] |
    // stats[3*NSLOT*128 = 6144] | wt1[4096] wt2[2048] wt3[2048] | col[E] |
    // pairs[nbuck*BCAP] | hs fp16 (N*32 fl) | y fp16 (N*32 fl) |
    // parts fp16 (4 planes, N*128 fl)
    float* ws = (float*)d_ws;
    float* dinv     = ws;
    int*   rowstart4 = (int*)(ws + N);
    int*   bcount   = (int*)(ws + 5 * (size_t)N + 4);
    int*   bbase    = bcount + 1024;
    float* stats    = (float*)(bbase + 1024);
    unsigned short* wt1 = (unsigned short*)(stats + 6144);
    unsigned short* wt2 = wt1 + 8192;
    unsigned short* wt3 = wt2 + 4096;
    int*   col      = (int*)(stats + 6144 + 8192);
    unsigned* pairs = (unsigned*)(col + E);
    float* hsbf     = (float*)(pairs + (size_t)nbuck * BCAP);
    ushort4* hsb4   = (ushort4*)hsbf;
    float* ybuf     = hsbf + (size_t)N * 32;
    half4* partsh   = (half4*)(ybuf + (size_t)N * 32);

    size_t need = (size_t)((char*)partsh + (size_t)N * 512 - (char*)d_ws);
    const bool sliced = ws_size >= need;

    float* stats1 = stats, *stats2 = stats + 2048, *stats3 = stats + 4096;

    // one memset covers bcount + bbase + stats (contiguous)
    (void)hipMemsetAsync(bcount, 0, (1024 + 1024 + 6144) * sizeof(int), stream);
    prep_wt_all<<<64, 256, 0, stream>>>(W1, W2, W3, wt1, wt2, wt3);
    partition_edges<<<(E + PART_CHUNK - 1) / PART_CHUNK, 256, 0, stream>>>(
        srcp, dstp, bcount, pairs, E, nbuck);
    scan_bcount<<<1, 1024, 0, stream>>>(bcount, bbase, rowstart4, N, E, nbuck);
    fill_csr_bucket<<<nbuck, 256, 0, stream>>>(pairs, bcount, bbase, rowstart4,
                                               dinv, col, N, s4f);

    const int gemmGrid = (N + 63) / 64;
    const int aggGrid = 4096;   // multiple of 8: groups (slice,half) via bid&7
    const int redGrid = (N * 8 + 255) / 256;   // one uint4 position per thread
    const int applyGrid = (N * 16 + 255) / 256;
    const float invN = 1.0f / (float)N;

    if (sliced) {
        // ---- layer 1 ----
        gemm_mfma<128, false><<<gemmGrid, 256, 0, stream>>>(
            x, wt1, dinv, nullptr, nullptr, nullptr, nullptr, invN, hsb4, N);
        aggregate_sliced<<<aggGrid, 256, 0, stream>>>((const uint4*)hsb4, col,
                                                      rowstart4, (uint4*)partsh,
                                                      N, s4f);
        reduce_bn<<<redGrid, 256, 0, stream>>>((const uint4*)partsh, dinv, b1,
                                               stats1, (uint4*)ybuf, N);

        // ---- layer 2 (BN1+PReLU1 inlined into X staging) ----
        gemm_mfma<64, true><<<gemmGrid, 256, 0, stream>>>(
            ybuf, wt2, dinv, stats1, g1, be1, a1, invN, hsb4, N);
        aggregate_sliced<<<aggGrid, 256, 0, stream>>>((const uint4*)hsb4, col,
                                                      rowstart4, (uint4*)partsh,
                                                      N, s4f);
        reduce_bn<<<redGrid, 256, 0, stream>>>((const uint4*)partsh, dinv, b2,
                                               stats2, (uint4*)ybuf, N);

        // ---- layer 3 ----
        gemm_mfma<64, true><<<gemmGrid, 256, 0, stream>>>(
            ybuf, wt3, dinv, stats2, g2, be2, a2, invN, hsb4, N);
        aggregate_sliced<<<aggGrid, 256, 0, stream>>>((const uint4*)hsb4, col,
                                                      rowstart4, (uint4*)partsh,
                                                      N, s4f);
        reduce_bn<<<redGrid, 256, 0, stream>>>((const uint4*)partsh, dinv, b3,
                                               stats3, (uint4*)ybuf, N);
    } else {
        // fallback: single-pass aggregate
        gemm_mfma<128, false><<<gemmGrid, 256, 0, stream>>>(
            x, wt1, dinv, nullptr, nullptr, nullptr, nullptr, invN, hsb4, N);
        aggregate_bn<<<2048, 256, 0, stream>>>(hsb4, col, rowstart4, dinv, b1,
                                               stats1, (uint2*)ybuf, N);
        gemm_mfma<64, true><<<gemmGrid, 256, 0, stream>>>(
            ybuf, wt2, dinv, stats1, g1, be1, a1, invN, hsb4, N);
        aggregate_bn<<<2048, 256, 0, stream>>>(hsb4, col, rowstart4, dinv, b2,
                                               stats2, (uint2*)ybuf, N);
        gemm_mfma<64, true><<<gemmGrid, 256, 0, stream>>>(
            ybuf, wt3, dinv, stats2, g2, be2, a2, invN, hsb4, N);
        aggregate_bn<<<2048, 256, 0, stream>>>(hsb4, col, rowstart4, dinv, b3,
                                               stats3, (uint2*)ybuf, N);
    }

    bn_apply<<<applyGrid, 256, 0, stream>>>((const uint2*)ybuf, stats3, g3, be3,
                                            a3, invN, (float4*)d_out, N * 16);
}

// Round 9
// 349.953 us; speedup vs baseline: 1.0904x; 1.0904x over previous
//
#include <hip/hip_runtime.h>

// GCN: 3 x (GCNConv -> BN(train) -> PReLU), N=100000, E=1600000, 128->64->64->64
// R18: partition_edges — decouple write locality from occupancy.
//   R17 post-mortem (FAILED): PART_CHUNK 8192->2048 raised occupancy 6.8->27%
//   but WRITE_SIZE doubled 20->42MB (write-run length = PART_CHUNK/nbuck
//   dropped 10.5->2.6 entries -> 4B-granule amplification); dur 44->60us.
//   Lesson: chunk size controls write-run length, block SIZE controls TLP.
//   Fix: PART_CHUNK back to 8192 (runs ~10.5, WRITE ~20MB) + 1024 thr/block
//   (196 blocks x 16 waves ~ 12 waves/CU, 4x R16's TLP), 8 edges/thread.
// R16: single-shot reduce (one uint4/thread) + 16-slot striped stats.
// R15/R13: windowed latency-flat gather + fp16 hs/y planes.
// R12: shuffle-free gather geometry (8-lane groups, full-lane epilogue).
// R11: FETCH=35MB == compulsory floor (8 XCD x 3.2MB slice + col).
// R10: src-sliced XCD-pinned gather; bid%8->XCD round-robin; CSR ordered
//   (bucket, local, slice): rowstart4[n*4+s].
// R9: bf16 MFMA GEMMs. R3: LDS-atomic aggregation = latency disaster.

constexpr float BN_EPS = 1e-5f;
constexpr int NB_SHIFT = 7;          // 128 nodes per bucket
constexpr int BCAP = 2560;           // pairs per bucket (avg 2048, ~11 sigma)
constexpr int PART_CHUNK = 8192;     // edges per partition block (write-run 10.5)
constexpr int PTHR = 1024;           // partition threads/block (R18: TLP knob)
constexpr int NSLOT = 16;            // striped stats slots

typedef __bf16 bf16x8 __attribute__((ext_vector_type(8)));
typedef float floatx4 __attribute__((ext_vector_type(4)));
typedef _Float16 half4 __attribute__((ext_vector_type(4)));
typedef _Float16 h2v __attribute__((ext_vector_type(2)));
typedef unsigned uintx4 __attribute__((ext_vector_type(4)));

__device__ inline unsigned short f2bf(float f) {
    unsigned u = __float_as_uint(f);
    unsigned r = (u + 0x7FFFu + ((u >> 16) & 1u)) >> 16;
    return (unsigned short)r;
}
__device__ inline unsigned short f2h(float f) {
    _Float16 h = (_Float16)f;
    return __builtin_bit_cast(unsigned short, h);
}
__device__ inline float h2f(unsigned short u) {
    return (float)__builtin_bit_cast(_Float16, u);
}
__device__ inline unsigned pack_h2(float a, float b) {
    h2v h = {(_Float16)a, (_Float16)b};
    return __builtin_bit_cast(unsigned, h);
}
__device__ inline int slice_of(int idx, float s4f) {
    int s = (int)((float)idx * s4f);
    return s > 3 ? 3 : s;
}
// accumulate 8 fp16 (one uint4) into 8 fp32
__device__ inline void addu4(uint4 r, float* A) {
    h2v h0 = __builtin_bit_cast(h2v, r.x);
    h2v h1 = __builtin_bit_cast(h2v, r.y);
    h2v h2 = __builtin_bit_cast(h2v, r.z);
    h2v h3 = __builtin_bit_cast(h2v, r.w);
    A[0] += (float)h0[0]; A[1] += (float)h0[1];
    A[2] += (float)h1[0]; A[3] += (float)h1[1];
    A[4] += (float)h2[0]; A[5] += (float)h2[1];
    A[6] += (float)h3[0]; A[7] += (float)h3[1];
}

// Partition edges into 128-node dst-buckets; packed entry = src | (local<<20).
// R18: 8192-edge chunks (write-run 10.5) x 1024 threads (16 waves/block).
__global__ __launch_bounds__(PTHR) void partition_edges(
    const int* __restrict__ src, const int* __restrict__ dst,
    int* __restrict__ bcount, unsigned* __restrict__ pairs, int E, int nbuck) {
    __shared__ int hist[1024];
    const int t = threadIdx.x;
    for (int i = t; i < nbuck; i += PTHR) hist[i] = 0;
    __syncthreads();
    const int e0 = blockIdx.x * PART_CHUNK;
    const int e1 = min(e0 + PART_CHUNK, E);
    int dloc[PART_CHUNK / PTHR];
    int cnt = 0;
    for (int e = e0 + t; e < e1; e += PTHR) {
        int d = dst[e];
        dloc[cnt++] = d;
        atomicAdd(&hist[d >> NB_SHIFT], 1);
    }
    __syncthreads();
    for (int i = t; i < nbuck; i += PTHR) {
        int c = hist[i];
        hist[i] = (c > 0) ? atomicAdd(&bcount[i], c) : 0;  // run base within bucket
    }
    __syncthreads();
    cnt = 0;
    for (int e = e0 + t; e < e1; e += PTHR) {
        int s = src[e], d = dloc[cnt++];
        int b = d >> NB_SHIFT;
        int pos = atomicAdd(&hist[b], 1);
        pairs[(size_t)b * BCAP + pos] = (unsigned)s | ((unsigned)(d & 127) << 20);
    }
}

// Exclusive scan of bcount[nbuck] -> bbase; also rowstart4[4N] = E sentinel.
__global__ __launch_bounds__(1024) void scan_bcount(
    const int* __restrict__ bcount, int* __restrict__ bbase,
    int* __restrict__ rowstart4, int N, int E, int nbuck) {
    __shared__ int tmp[1024];
    const int t = threadIdx.x;
    int v = (t < nbuck) ? bcount[t] : 0;
    tmp[t] = v;
    __syncthreads();
    for (int off = 1; off < 1024; off <<= 1) {
        int u = (t >= off) ? tmp[t - off] : 0;
        __syncthreads();
        tmp[t] += u;
        __syncthreads();
    }
    if (t < nbuck) bbase[t] = tmp[t] - v;  // exclusive
    if (t == 0) rowstart4[4 * N] = E;
}

// One block per bucket: LDS (local,slice) histogram -> scan -> rowstart4/dinv,
// then cursor fill of col ordered by (local, slice) within the bucket window.
__global__ __launch_bounds__(256) void fill_csr_bucket(
    const unsigned* __restrict__ pairs, const int* __restrict__ bcount,
    const int* __restrict__ bbase, int* __restrict__ rowstart4,
    float* __restrict__ dinv, int* __restrict__ col, int N, float s4f) {
    __shared__ int hist[512], pfx[512];
    const int b = blockIdx.x, t = threadIdx.x;
    hist[t] = 0; hist[t + 256] = 0;
    __syncthreads();
    const int cnt = bcount[b];
    const unsigned* pp = pairs + (size_t)b * BCAP;
    for (int e = t; e < cnt; e += 256) {
        unsigned pr = pp[e];
        int srcv = (int)(pr & 0xFFFFFu);
        atomicAdd(&hist[((pr >> 20) << 2) + slice_of(srcv, s4f)], 1);
    }
    __syncthreads();
    pfx[t] = hist[t]; pfx[t + 256] = hist[t + 256];
    __syncthreads();
    for (int off = 1; off < 512; off <<= 1) {
        int v0 = (t >= off) ? pfx[t - off] : 0;
        int v1 = pfx[t + 256 - off];  // t+256 >= 256 >= off always
        __syncthreads();
        if (t >= off) pfx[t] += v0;
        pfx[t + 256] += v1;
        __syncthreads();
    }
    const int base = bbase[b];
    if (t < 128) {
        int excl0 = pfx[t * 4] - hist[t * 4];
        int degTot = pfx[t * 4 + 3] - excl0;
        int n = (b << NB_SHIFT) + t;
        if (n < N) dinv[n] = rsqrtf((float)degTot + 1.0f);  // +1 self-loop
    }
    __syncthreads();
    // per-(local,slice) start -> rowstart4 and cursor
    {
        int i0 = t, i1 = t + 256;
        int st0 = base + pfx[i0] - hist[i0];
        int st1 = base + pfx[i1] - hist[i1];
        int n0 = (b << NB_SHIFT) + (i0 >> 2);
        int n1 = (b << NB_SHIFT) + (i1 >> 2);
        if (n0 < N) rowstart4[(n0 << 2) + (i0 & 3)] = st0;
        if (n1 < N) rowstart4[(n1 << 2) + (i1 & 3)] = st1;
        hist[i0] = st0; hist[i1] = st1;
    }
    __syncthreads();
    for (int e = t; e < cnt; e += 256) {
        unsigned pr = pp[e];
        int srcv = (int)(pr & 0xFFFFFu);
        int pos = atomicAdd(&hist[((pr >> 20) << 2) + slice_of(srcv, s4f)], 1);
        col[pos] = srcv;
    }
}

// Transpose + bf16-convert all three W matrices: wt[n*K + k] = bf16(W[k][n]).
__global__ __launch_bounds__(256) void prep_wt_all(
    const float* __restrict__ W1, const float* __restrict__ W2,
    const float* __restrict__ W3, unsigned short* __restrict__ wt1,
    unsigned short* __restrict__ wt2, unsigned short* __restrict__ wt3) {
    const int b = blockIdx.x, t = threadIdx.x;
    const float* W;
    unsigned short* wt;
    int K, base;
    if (b < 32)      { W = W1; wt = wt1; K = 128; base = b * 256; }
    else if (b < 48) { W = W2; wt = wt2; K = 64;  base = (b - 32) * 256; }
    else             { W = W3; wt = wt3; K = 64;  base = (b - 48) * 256; }
    int i = base + t;
    if (i < K * 64) {
        int k = i >> 6, n = i & 63;
        wt[n * K + k] = f2bf(W[i]);
    }
}

// MFMA bf16 GEMM: hs[row][c] = fp16( (X'[row][:] @ W[:][c]) * dinv[row] ).
// FUSE: X' = prelu(bn(X), a), X stored fp16; scale/shift from 16-slot stats.
// Block: 256 thr = 4 waves; 64 rows x 64 cols; wave w owns rows 16w..16w+15.
template <int K, bool FUSE>
__global__ __launch_bounds__(256) void gemm_mfma(
    const float* __restrict__ X, const unsigned short* __restrict__ wt,
    const float* __restrict__ dinv, const float* __restrict__ stats_prev,
    const float* __restrict__ g_prev, const float* __restrict__ be_prev,
    const float* __restrict__ a_prev, float invN,
    ushort4* __restrict__ hsb4, int N) {
    constexpr int XS = K + 8;  // LDS row stride in bf16 units (pad 16B)
    __shared__ unsigned short Xs[64 * XS];
    __shared__ unsigned short Wts[64 * XS];
    __shared__ float scs[64], shs[64];

    const int t = threadIdx.x;
    const int rowBase = blockIdx.x * 64;

    if (FUSE && t < 64) {
        float ms = 0.f, qs = 0.f;
#pragma unroll
        for (int k = 0; k < NSLOT; ++k) {
            ms += stats_prev[k * 128 + t];
            qs += stats_prev[k * 128 + 64 + t];
        }
        float mu = ms * invN;
        float var = qs * invN - mu * mu;
        float sc = g_prev[t] * rsqrtf(var + BN_EPS);
        scs[t] = sc;
        shs[t] = fmaf(-mu, sc, be_prev[t]);
    }

    // stage Wt (64 rows x K bf16) via uint4
    constexpr int U4R = K / 8;  // uint4 per wt row
#pragma unroll
    for (int j = 0; j < (64 * U4R) / 256; ++j) {
        int idx = t + j * 256;
        int n = idx / U4R, ch = idx % U4R;
        uint4 v = *(const uint4*)&wt[n * K + ch * 8];
        *(uint4*)&Wts[n * XS + ch * 8] = v;
    }
    __syncthreads();  // scs + Wts visible

    // stage Xs: 64 rows x K -> (FUSE: fp16 + BN/PReLU) -> bf16
    constexpr int F4R = K / 4;  // 4-feature chunks per X row
#pragma unroll
    for (int j = 0; j < (64 * F4R) / 256; ++j) {
        int idx = t + j * 256;
        int r = idx / F4R, c4 = idx % F4R;
        int row = rowBase + r;
        float4 v = make_float4(0.f, 0.f, 0.f, 0.f);
        if (row < N) {
            if (FUSE) {
                const unsigned short* Xh = (const unsigned short*)X;
                uint2 hv = *(const uint2*)(Xh + (size_t)row * 64 + c4 * 4);
                h2v p = __builtin_bit_cast(h2v, hv.x);
                h2v q = __builtin_bit_cast(h2v, hv.y);
                v = make_float4((float)p[0], (float)p[1], (float)q[0], (float)q[1]);
                int c = c4 * 4;
                float4 av = ((const float4*)a_prev)[c4];
                v.x = fmaf(v.x, scs[c + 0], shs[c + 0]); v.x = v.x >= 0.f ? v.x : av.x * v.x;
                v.y = fmaf(v.y, scs[c + 1], shs[c + 1]); v.y = v.y >= 0.f ? v.y : av.y * v.y;
                v.z = fmaf(v.z, scs[c + 2], shs[c + 2]); v.z = v.z >= 0.f ? v.z : av.z * v.z;
                v.w = fmaf(v.w, scs[c + 3], shs[c + 3]); v.w = v.w >= 0.f ? v.w : av.w * v.w;
            } else {
                v = *(const float4*)(X + (size_t)row * K + c4 * 4);
            }
        }
        ushort4 o;
        o.x = f2bf(v.x); o.y = f2bf(v.y); o.z = f2bf(v.z); o.w = f2bf(v.w);
        *(ushort4*)&Xs[r * XS + c4 * 4] = o;
    }
    __syncthreads();

    const int w = t >> 6;        // wave 0..3 -> rows 16w..16w+15
    const int l = t & 63;
    const int q = l >> 4;        // quad: k-offset q*8
    const int m = l & 15;        // A row / B col within tile

    floatx4 acc[4];
#pragma unroll
    for (int ct = 0; ct < 4; ++ct) acc[ct] = {0.f, 0.f, 0.f, 0.f};

#pragma unroll
    for (int ks = 0; ks < K / 32; ++ks) {
        bf16x8 a = *(const bf16x8*)&Xs[(16 * w + m) * XS + ks * 32 + q * 8];
#pragma unroll
        for (int ct = 0; ct < 4; ++ct) {
            bf16x8 b = *(const bf16x8*)&Wts[(ct * 16 + m) * XS + ks * 32 + q * 8];
            acc[ct] = __builtin_amdgcn_mfma_f32_16x16x32_bf16(a, b, acc[ct], 0, 0, 0);
        }
    }

    // dinv per owned row (C/D layout: row = q*4 + r, col = m)
    float dv[4];
#pragma unroll
    for (int r = 0; r < 4; ++r) {
        int row = rowBase + 16 * w + q * 4 + r;
        dv[r] = (row < N) ? dinv[row] : 0.f;
    }

    __syncthreads();  // done reading Xs; reuse as C staging (64 x 72 fp16)
    unsigned short* Cs = Xs;
#pragma unroll
    for (int ct = 0; ct < 4; ++ct)
#pragma unroll
        for (int r = 0; r < 4; ++r)
            Cs[(16 * w + q * 4 + r) * 72 + ct * 16 + m] = f2h(acc[ct][r] * dv[r]);
    __syncthreads();

    // coalesced write-out: 64 rows x 8 uint4 (row = 64 fp16)
#pragma unroll
    for (int j = 0; j < 2; ++j) {
        int idx = t + j * 256;
        int r = idx >> 3, ch = idx & 7;
        int row = rowBase + r;
        if (row < N) {
            uint4 v = *(const uint4*)&Cs[r * 72 + ch * 8];
            ((uint4*)hsb4)[(size_t)row * 8 + ch] = v;
        }
    }
}

// Gather: block group g = bid&7 -> slice s = g>>1, node-half h = g&1
// (bid%8 -> XCD round-robin keeps each XCD on one 3.2MB L2-resident slice).
// 8-lane group owns one (node,slice): lane = feature octet (16B), wave = 8
// consecutive nodes. Windowed: 4 clamp-indexed col loads together, then 4 row
// loads together (zero-masked past deg); windows at deg>4/>8, serial tail >12.
// Self term added by the slice containing n (L2-hit). 1KB contiguous NT stores.
__global__ __launch_bounds__(256) void aggregate_sliced(
    const uint4* __restrict__ hsp, const int* __restrict__ col,
    const int* __restrict__ rs4, uint4* __restrict__ parts, int N, float s4f) {
    const int t = threadIdx.x;
    const int lane = t & 63;
    const int wid = t >> 6;      // wave in block (0..3)
    const int fl = lane & 7;     // feature octet index (16B)
    const int grp = lane >> 3;   // node subgroup (0..7)
    const int g = blockIdx.x & 7;
    const int s = g >> 1;        // src slice 0..3
    const int h = g & 1;         // node half
    const int r = blockIdx.x >> 3;
    const int H = (N + 1) >> 1;
    const int n0 = h * H;
    const int n1 = min(N, n0 + H);
    const int stride = ((gridDim.x >> 3) << 2) << 3;  // waves/group * 8 nodes
    uint4* plane = parts + (size_t)s * ((size_t)N * 8);

    for (int nb = n0 + (((r << 2) + wid) << 3); nb < n1; nb += stride) {
        const int n = nb + grp;
        const bool valid = n < n1;
        int start = 0, deg = 0;
        if (valid) {
            start = rs4[(n << 2) + s];
            deg = rs4[(n << 2) + s + 1] - start;
        }
        float A[8] = {0.f, 0.f, 0.f, 0.f, 0.f, 0.f, 0.f, 0.f};
        float B[8] = {0.f, 0.f, 0.f, 0.f, 0.f, 0.f, 0.f, 0.f};
        const uint4 z = {0u, 0u, 0u, 0u};
#pragma unroll
        for (int wnd = 0; wnd < 3; ++wnd) {
            const int o = wnd * 4;
            if (deg > o) {
                int d1 = deg - 1;
                int j1 = min(o + 1, d1), j2 = min(o + 2, d1), j3 = min(o + 3, d1);
                int e0 = col[start + o];
                int e1 = col[start + j1];
                int e2 = col[start + j2];
                int e3 = col[start + j3];
                uint4 r0 = hsp[(size_t)e0 * 8 + fl];
                uint4 r1 = hsp[(size_t)e1 * 8 + fl];
                uint4 r2 = hsp[(size_t)e2 * 8 + fl];
                uint4 r3 = hsp[(size_t)e3 * 8 + fl];
                if (o + 1 >= deg) r1 = z;
                if (o + 2 >= deg) r2 = z;
                if (o + 3 >= deg) r3 = z;
                addu4(r0, A); addu4(r1, B); addu4(r2, A); addu4(r3, B);
            }
        }
        for (int it = 12; it < deg; ++it) {  // P(deg>12) ~ 0.06%
            int e0 = col[start + it];
            addu4(hsp[(size_t)e0 * 8 + fl], A);
        }
        if (valid && slice_of(n, s4f) == s) {  // self term, slice-local (L2-hit)
            addu4(hsp[(size_t)n * 8 + fl], B);
        }
        if (valid) {
            uintx4 ov;
            ov[0] = pack_h2(A[0] + B[0], A[1] + B[1]);
            ov[1] = pack_h2(A[2] + B[2], A[3] + B[3]);
            ov[2] = pack_h2(A[4] + B[4], A[5] + B[5]);
            ov[3] = pack_h2(A[6] + B[6], A[7] + B[7]);
            __builtin_nontemporal_store(ov, (uintx4*)&plane[(size_t)n * 8 + fl]);
        }
    }
}

// Single-shot reduce: grid = N*8/256 blocks, one uint4 position per thread
// (node = i>>3, feature octet = i&7). y = dinv*(sum_s parts[s]) + bias (self
// already in planes). Stats: shfl_xor(8/16/32) wave pre-reduce -> LDS ->
// 16-slot striped global atomics (consumers sum the slots).
__global__ __launch_bounds__(256) void reduce_bn(
    const uint4* __restrict__ parts, const float* __restrict__ dinv,
    const float* __restrict__ bias, float* __restrict__ stats,
    uint4* __restrict__ y4h, int N) {
    const int t = threadIdx.x;
    const size_t NP4 = (size_t)N * 8;
    const size_t i = (size_t)blockIdx.x * 256 + t;
    const int fo = (int)(i & 7);  // feature octet (features fo*8 .. fo*8+7)
    __shared__ float lsum[64], lsq[64];
    if (t < 64) { lsum[t] = 0.f; lsq[t] = 0.f; }
    __syncthreads();

    float S[8] = {0.f, 0.f, 0.f, 0.f, 0.f, 0.f, 0.f, 0.f};
    float Q[8] = {0.f, 0.f, 0.f, 0.f, 0.f, 0.f, 0.f, 0.f};
    if (i < NP4) {
        uint4 p0 = parts[i];
        uint4 p1 = parts[NP4 + i];
        uint4 p2 = parts[2 * NP4 + i];
        uint4 p3 = parts[3 * NP4 + i];
        float dv = dinv[i >> 3];
        float4 bA = ((const float4*)bias)[fo * 2];
        float4 bB = ((const float4*)bias)[fo * 2 + 1];
        float bb[8] = {bA.x, bA.y, bA.z, bA.w, bB.x, bB.y, bB.z, bB.w};
        unsigned u0[4] = {p0.x, p0.y, p0.z, p0.w};
        unsigned u1[4] = {p1.x, p1.y, p1.z, p1.w};
        unsigned u2[4] = {p2.x, p2.y, p2.z, p2.w};
        unsigned u3[4] = {p3.x, p3.y, p3.z, p3.w};
        uintx4 ov;
#pragma unroll
        for (int k = 0; k < 4; ++k) {
            h2v a = __builtin_bit_cast(h2v, u0[k]);
            h2v b = __builtin_bit_cast(h2v, u1[k]);
            h2v c = __builtin_bit_cast(h2v, u2[k]);
            h2v d = __builtin_bit_cast(h2v, u3[k]);
            float y0 = fmaf(dv, (float)a[0] + (float)b[0] + (float)c[0] + (float)d[0], bb[2 * k]);
            float y1 = fmaf(dv, (float)a[1] + (float)b[1] + (float)c[1] + (float)d[1], bb[2 * k + 1]);
            S[2 * k] = y0; Q[2 * k] = y0 * y0;
            S[2 * k + 1] = y1; Q[2 * k + 1] = y1 * y1;
            ov[k] = pack_h2(y0, y1);
        }
        *(uintx4*)&y4h[i] = ov;
    }
    // wave reduce across lanes with the same (lane&7) == feature octet
#pragma unroll
    for (int k = 0; k < 8; ++k) {
        S[k] += __shfl_xor(S[k], 8);  Q[k] += __shfl_xor(Q[k], 8);
        S[k] += __shfl_xor(S[k], 16); Q[k] += __shfl_xor(Q[k], 16);
        S[k] += __shfl_xor(S[k], 32); Q[k] += __shfl_xor(Q[k], 32);
    }
    if ((t & 63) < 8) {
        const int base = (t & 7) * 8;
#pragma unroll
        for (int k = 0; k < 8; ++k) {
            atomicAdd(&lsum[base + k], S[k]);
            atomicAdd(&lsq[base + k], Q[k]);
        }
    }
    __syncthreads();
    const int slot = blockIdx.x & (NSLOT - 1);
    if (t < 64) atomicAdd(&stats[slot * 128 + t], lsum[t]);
    else if (t < 128) atomicAdd(&stats[slot * 128 + 64 + (t - 64)], lsq[t - 64]);
}

// Fallback (ws too small for planes): single-pass aggregate, fp16 hs/y,
// 16-slot striped stats.
__global__ __launch_bounds__(256) void aggregate_bn(
    const ushort4* __restrict__ hsb4, const int* __restrict__ col,
    const int* __restrict__ rs4, const float* __restrict__ dinv,
    const float* __restrict__ bias, float* __restrict__ stats,
    uint2* __restrict__ y2, int N) {
    const int t = threadIdx.x;
    const int lane = t & 63;
    const int wid = t >> 6;
    const int fl = lane & 15;
    const int eg = lane >> 4;

    __shared__ float lsum[64], lsq[64];
    if (t < 64) { lsum[t] = 0.f; lsq[t] = 0.f; }
    __syncthreads();

    float4 ssum = make_float4(0.f, 0.f, 0.f, 0.f);
    float4 ssq  = make_float4(0.f, 0.f, 0.f, 0.f);
    const float4 b4 = ((const float4*)bias)[fl];
    const int waveStride = gridDim.x * 4;

    for (int n = blockIdx.x * 4 + wid; n < N; n += waveStride) {
        int start = rs4[n * 4];
        int deg = rs4[n * 4 + 4] - start;
        float4 acc = make_float4(0.f, 0.f, 0.f, 0.f);
        for (int i = eg; i < deg; i += 4) {
            int s = col[start + i];
            ushort4 rv = hsb4[(size_t)s * 16 + fl];
            acc.x += h2f(rv.x); acc.y += h2f(rv.y);
            acc.z += h2f(rv.z); acc.w += h2f(rv.w);
        }
        acc.x += __shfl_xor(acc.x, 16); acc.y += __shfl_xor(acc.y, 16);
        acc.z += __shfl_xor(acc.z, 16); acc.w += __shfl_xor(acc.w, 16);
        acc.x += __shfl_xor(acc.x, 32); acc.y += __shfl_xor(acc.y, 32);
        acc.z += __shfl_xor(acc.z, 32); acc.w += __shfl_xor(acc.w, 32);
        if (eg == 0) {
            ushort4 sv = hsb4[(size_t)n * 16 + fl];
            float dv = dinv[n];
            float yx = fmaf(dv, acc.x + h2f(sv.x), b4.x);
            float yy = fmaf(dv, acc.y + h2f(sv.y), b4.y);
            float yz = fmaf(dv, acc.z + h2f(sv.z), b4.z);
            float yw = fmaf(dv, acc.w + h2f(sv.w), b4.w);
            uint2 yv;
            yv.x = pack_h2(yx, yy);
            yv.y = pack_h2(yz, yw);
            y2[(size_t)n * 16 + fl] = yv;
            ssum.x += yx; ssum.y += yy; ssum.z += yz; ssum.w += yw;
            ssq.x = fmaf(yx, yx, ssq.x); ssq.y = fmaf(yy, yy, ssq.y);
            ssq.z = fmaf(yz, yz, ssq.z); ssq.w = fmaf(yw, yw, ssq.w);
        }
    }
    if (eg == 0) {
        atomicAdd(&lsum[fl * 4 + 0], ssum.x); atomicAdd(&lsum[fl * 4 + 1], ssum.y);
        atomicAdd(&lsum[fl * 4 + 2], ssum.z); atomicAdd(&lsum[fl * 4 + 3], ssum.w);
        atomicAdd(&lsq[fl * 4 + 0], ssq.x);  atomicAdd(&lsq[fl * 4 + 1], ssq.y);
        atomicAdd(&lsq[fl * 4 + 2], ssq.z);  atomicAdd(&lsq[fl * 4 + 3], ssq.w);
    }
    __syncthreads();
    const int slot = blockIdx.x & (NSLOT - 1);
    if (t < 64) atomicAdd(&stats[slot * 128 + t], lsum[t]);
    else if (t < 128) atomicAdd(&stats[slot * 128 + 64 + (t - 64)], lsq[t - 64]);
}

// final layer: out = prelu(bn(y), a), y fp16, scale/shift from 16-slot stats
// (precomputed once per block into LDS).
__global__ __launch_bounds__(256) void bn_apply(
    const uint2* __restrict__ y2, const float* __restrict__ stats,
    const float* __restrict__ g, const float* __restrict__ be,
    const float* __restrict__ a, float invN, float4* __restrict__ out4,
    int total4) {
    __shared__ float scs[64], shs[64], as[64];
    const int t = threadIdx.x;
    if (t < 64) {
        float ms = 0.f, qs = 0.f;
#pragma unroll
        for (int k = 0; k < NSLOT; ++k) {
            ms += stats[k * 128 + t];
            qs += stats[k * 128 + 64 + t];
        }
        float mu = ms * invN;
        float var = qs * invN - mu * mu;
        float sc = g[t] * rsqrtf(var + BN_EPS);
        scs[t] = sc;
        shs[t] = fmaf(-mu, sc, be[t]);
        as[t] = a[t];
    }
    __syncthreads();
    int i = blockIdx.x * blockDim.x + t;
    if (i >= total4) return;
    int cg = (i & 15) * 4;
    uint2 hv = y2[i];
    h2v p = __builtin_bit_cast(h2v, hv.x);
    h2v q = __builtin_bit_cast(h2v, hv.y);
    float vv[4] = {(float)p[0], (float)p[1], (float)q[0], (float)q[1]};
    float4 o;
#pragma unroll
    for (int j = 0; j < 4; ++j) {
        int c = cg + j;
        float z = fmaf(vv[j], scs[c], shs[c]);
        z = z >= 0.f ? z : as[c] * z;
        if (j == 0) o.x = z; else if (j == 1) o.y = z; else if (j == 2) o.z = z; else o.w = z;
    }
    out4[i] = o;
}

extern "C" void kernel_launch(void* const* d_in, const int* in_sizes, int n_in,
                              void* d_out, int out_size, void* d_ws, size_t ws_size,
                              hipStream_t stream) {
    const float* x  = (const float*)d_in[0];
    const int*   ei = (const int*)d_in[1];
    const int N = in_sizes[0] / 128;
    const int E = in_sizes[1] / 2;
    const int* srcp = ei;
    const int* dstp = ei + E;

    const float* W1 = (const float*)d_in[2];
    const float* b1 = (const float*)d_in[3];
    const float* g1 = (const float*)d_in[4];
    const float* be1 = (const float*)d_in[5];
    const float* a1 = (const float*)d_in[6];
    const float* W2 = (const float*)d_in[7];
    const float* b2 = (const float*)d_in[8];
    const float* g2 = (const float*)d_in[9];
    const float* be2 = (const float*)d_in[10];
    const float* a2 = (const float*)d_in[11];
    const float* W3 = (const float*)d_in[12];
    const float* b3 = (const float*)d_in[13];
    const float* g3 = (const float*)d_in[14];
    const float* be3 = (const float*)d_in[15];
    const float* a3 = (const float*)d_in[16];

    const int nbuck = (N + 127) >> NB_SHIFT;  // 782
    const float s4f = 4.0f / (float)N;

    // ws layout (4B units):
    // dinv[N] | rowstart4[4N+4] | bcount[1024] | bbase[1024] |
    // stats[3*NSLOT*128 = 6144] | wt1[4096] wt2[2048] wt3[2048] | col[E] |
    // pairs[nbuck*BCAP] | hs fp16 (N*32 fl) | y fp16 (N*32 fl) |
    // parts fp16 (4 planes, N*128 fl)
    float* ws = (float*)d_ws;
    float* dinv     = ws;
    int*   rowstart4 = (int*)(ws + N);
    int*   bcount   = (int*)(ws + 5 * (size_t)N + 4);
    int*   bbase    = bcount + 1024;
    float* stats    = (float*)(bbase + 1024);
    unsigned short* wt1 = (unsigned short*)(stats + 6144);
    unsigned short* wt2 = wt1 + 8192;
    unsigned short* wt3 = wt2 + 4096;
    int*   col      = (int*)(stats + 6144 + 8192);
    unsigned* pairs = (unsigned*)(col + E);
    float* hsbf     = (float*)(pairs + (size_t)nbuck * BCAP);
    ushort4* hsb4   = (ushort4*)hsbf;
    float* ybuf     = hsbf + (size_t)N * 32;
    half4* partsh   = (half4*)(ybuf + (size_t)N * 32);

    size_t need = (size_t)((char*)partsh + (size_t)N * 512 - (char*)d_ws);
    const bool sliced = ws_size >= need;

    float* stats1 = stats, *stats2 = stats + 2048, *stats3 = stats + 4096;

    // one memset covers bcount + bbase + stats (contiguous)
    (void)hipMemsetAsync(bcount, 0, (1024 + 1024 + 6144) * sizeof(int), stream);
    prep_wt_all<<<64, 256, 0, stream>>>(W1, W2, W3, wt1, wt2, wt3);
    partition_edges<<<(E + PART_CHUNK - 1) / PART_CHUNK, PTHR, 0, stream>>>(
        srcp, dstp, bcount, pairs, E, nbuck);
    scan_bcount<<<1, 1024, 0, stream>>>(bcount, bbase, rowstart4, N, E, nbuck);
    fill_csr_bucket<<<nbuck, 256, 0, stream>>>(pairs, bcount, bbase, rowstart4,
                                               dinv, col, N, s4f);

    const int gemmGrid = (N + 63) / 64;
    const int aggGrid = 4096;   // multiple of 8: groups (slice,half) via bid&7
    const int redGrid = (N * 8 + 255) / 256;   // one uint4 position per thread
    const int applyGrid = (N * 16 + 255) / 256;
    const float invN = 1.0f / (float)N;

    if (sliced) {
        // ---- layer 1 ----
        gemm_mfma<128, false><<<gemmGrid, 256, 0, stream>>>(
            x, wt1, dinv, nullptr, nullptr, nullptr, nullptr, invN, hsb4, N);
        aggregate_sliced<<<aggGrid, 256, 0, stream>>>((const uint4*)hsb4, col,
                                                      rowstart4, (uint4*)partsh,
                                                      N, s4f);
        reduce_bn<<<redGrid, 256, 0, stream>>>((const uint4*)partsh, dinv, b1,
                                               stats1, (uint4*)ybuf, N);

        // ---- layer 2 (BN1+PReLU1 inlined into X staging) ----
        gemm_mfma<64, true><<<gemmGrid, 256, 0, stream>>>(
            ybuf, wt2, dinv, stats1, g1, be1, a1, invN, hsb4, N);
        aggregate_sliced<<<aggGrid, 256, 0, stream>>>((const uint4*)hsb4, col,
                                                      rowstart4, (uint4*)partsh,
                                                      N, s4f);
        reduce_bn<<<redGrid, 256, 0, stream>>>((const uint4*)partsh, dinv, b2,
                                               stats2, (uint4*)ybuf, N);

        // ---- layer 3 ----
        gemm_mfma<64, true><<<gemmGrid, 256, 0, stream>>>(
            ybuf, wt3, dinv, stats2, g2, be2, a2, invN, hsb4, N);
        aggregate_sliced<<<aggGrid, 256, 0, stream>>>((const uint4*)hsb4, col,
                                                      rowstart4, (uint4*)partsh,
                                                      N, s4f);
        reduce_bn<<<redGrid, 256, 0, stream>>>((const uint4*)partsh, dinv, b3,
                                               stats3, (uint4*)ybuf, N);
    } else {
        // fallback: single-pass aggregate
        gemm_mfma<128, false><<<gemmGrid, 256, 0, stream>>>(
            x, wt1, dinv, nullptr, nullptr, nullptr, nullptr, invN, hsb4, N);
        aggregate_bn<<<2048, 256, 0, stream>>>(hsb4, col, rowstart4, dinv, b1,
                                               stats1, (uint2*)ybuf, N);
        gemm_mfma<64, true><<<gemmGrid, 256, 0, stream>>>(
            ybuf, wt2, dinv, stats1, g1, be1, a1, invN, hsb4, N);
        aggregate_bn<<<2048, 256, 0, stream>>>(hsb4, col, rowstart4, dinv, b2,
                                               stats2, (uint2*)ybuf, N);
        gemm_mfma<64, true><<<gemmGrid, 256, 0, stream>>>(
            ybuf, wt3, dinv, stats2, g2, be2, a2, invN, hsb4, N);
        aggregate_bn<<<2048, 256, 0, stream>>>(hsb4, col, rowstart4, dinv, b3,
                                               stats3, (uint2*)ybuf, N);
    }

    bn_apply<<<applyGrid, 256, 0, stream>>>((const uint2*)ybuf, stats3, g3, be3,
                                            a3, invN, (float4*)d_out, N * 16);
}